// Round 1
// baseline (324.538 us; speedup 1.0000x reference)
//
#include <hip/hip_runtime.h>
#include <math.h>

#define SLOPE  0.2f
#define LATENT 64
#define HID    64
#define IN_DIM 129      // LAGS*LATENT + 1
#define LEN    512
#define NBATCH 32
#define TROWS  514      // LEN + LAGS
#define BN     128      // n-tile per block
#define XROWS  (BN + 2) // 130 staged x rows
#define XSTR   68       // LDS row stride for x (16B-aligned, bank-step 4)
#define BSTR   132      // LDS row stride for W1[l] (16B-aligned, bank-step 4)

__global__ __launch_bounds__(256, 2)
void fused_tvp(const float* __restrict__ xg, const float* __restrict__ W1g,
               const float* __restrict__ b1g, const float* __restrict__ W2g,
               const float* __restrict__ b2g,
               float* __restrict__ out_res, float* __restrict__ out_lad)
{
    __shared__ float sX[XROWS][XSTR];
    __shared__ float sB[HID][BSTR];

    const int tid  = threadIdx.x;
    const int tile = blockIdx.x;   // 0..127  (4 tiles per batch row)
    const int l    = blockIdx.y;   // 0..63
    const int bb   = tile >> 2;
    const int t0   = (tile & 3) * BN;

    // --- stage x rows t0 .. t0+129 (130 rows x 64 floats) ---
    {
        const float* src = xg + ((size_t)bb * TROWS + t0) * LATENT;
        for (int i = tid; i < XROWS * (LATENT / 4); i += 256) {
            const int row = i >> 4;
            const int col = (i & 15) << 2;
            *reinterpret_cast<float4*>(&sX[row][col]) =
                *reinterpret_cast<const float4*>(src + row * LATENT + col);
        }
    }
    // --- stage W1[l] : 64 rows x 129 floats ---
    {
        const float* src = W1g + (size_t)l * HID * IN_DIM;
        for (int i = tid; i < HID * IN_DIM; i += 256) {
            const int h = i / IN_DIM;
            const int d = i - h * IN_DIM;
            sB[h][d] = src[i];
        }
    }
    __syncthreads();

    const int tx = tid & 15;   // h-group
    const int ty = tid >> 4;   // n-group

    float acc[8][4];
    #pragma unroll
    for (int i = 0; i < 8; ++i)
        #pragma unroll
        for (int j = 0; j < 4; ++j) acc[i][j] = 0.f;

    // main GEMM: pre(acc) += lagsx . W1_lags^T
    #pragma unroll
    for (int half = 0; half < 2; ++half) {
        #pragma unroll 4
        for (int dd = 0; dd < 64; dd += 4) {
            float4 bv[4];
            #pragma unroll
            for (int j = 0; j < 4; ++j)
                bv[j] = *reinterpret_cast<const float4*>(&sB[tx + 16 * j][half * 64 + dd]);
            #pragma unroll
            for (int i = 0; i < 8; ++i) {
                const float4 av =
                    *reinterpret_cast<const float4*>(&sX[ty + 16 * i + half][dd]);
                #pragma unroll
                for (int j = 0; j < 4; ++j) {
                    acc[i][j] = fmaf(av.x, bv[j].x, acc[i][j]);
                    acc[i][j] = fmaf(av.y, bv[j].y, acc[i][j]);
                    acc[i][j] = fmaf(av.z, bv[j].z, acc[i][j]);
                    acc[i][j] = fmaf(av.w, bv[j].w, acc[i][j]);
                }
            }
        }
    }

    // epilogue: + xt*w1t + b1, leaky-relu, h-reductions
    float w1t[4], w2[4], bia[4];
    #pragma unroll
    for (int j = 0; j < 4; ++j) {
        const int h = tx + 16 * j;
        w1t[j] = sB[h][128];
        w2[j]  = W2g[l * HID + h];
        bia[j] = b1g[l * HID + h];
    }
    const float b2v = b2g[l];

    float res[8], jac[8];
    #pragma unroll
    for (int i = 0; i < 8; ++i) {
        const int nloc = ty + 16 * i;
        const float xt = sX[nloc + 2][l];
        float r = 0.f, jv = 0.f;
        #pragma unroll
        for (int j = 0; j < 4; ++j) {
            const float pre = acc[i][j] + xt * w1t[j] + bia[j];
            const float act = (pre >= 0.f) ? pre : SLOPE * pre;
            const float da  = (pre >= 0.f) ? 1.f : SLOPE;
            r  += act * w2[j];
            jv += w2[j] * da * w1t[j];
        }
        res[i] = r;
        jac[i] = jv;
    }

    // reduce over tx (16 lanes) via xor-shuffle
    #pragma unroll
    for (int m = 1; m <= 8; m <<= 1) {
        #pragma unroll
        for (int i = 0; i < 8; ++i) {
            res[i] += __shfl_xor(res[i], m);
            jac[i] += __shfl_xor(jac[i], m);
        }
    }

    if (tx == 0) {
        #pragma unroll
        for (int i = 0; i < 8; ++i) {
            const int ng = bb * LEN + t0 + ty + 16 * i;
            out_res[(size_t)ng * LATENT + l] = res[i] + b2v;
            atomicAdd(&out_lad[ng], logf(fabsf(jac[i])));
        }
    }
}

extern "C" void kernel_launch(void* const* d_in, const int* in_sizes, int n_in,
                              void* d_out, int out_size, void* d_ws, size_t ws_size,
                              hipStream_t stream) {
    const float* xg  = (const float*)d_in[0];
    const float* W1g = (const float*)d_in[1];
    const float* b1g = (const float*)d_in[2];
    const float* W2g = (const float*)d_in[3];
    const float* b2g = (const float*)d_in[4];

    float* out_res = (float*)d_out;
    float* out_lad = out_res + (size_t)NBATCH * LEN * LATENT;

    hipMemsetAsync(out_lad, 0, (size_t)NBATCH * LEN * sizeof(float), stream);

    dim3 grid(128, 64);  // (n-tiles, l)
    fused_tvp<<<grid, 256, 0, stream>>>(xg, W1g, b1g, W2g, b2g, out_res, out_lad);
}

// Round 3
// 180.392 us; speedup vs baseline: 1.7991x; 1.7991x over previous
//
#include <hip/hip_runtime.h>
#include <math.h>

#define SLOPE  0.2f
#define NB     32
#define LEN    512
#define LATENT 64
#define HID    64
#define IN_DIM 129
#define TROWS  514
#define NTOT   (NB * LEN)      // 16384
#define XROWS  130
#define XSTR   72              // ushort stride: 144 B, 16B-aligned

typedef __attribute__((ext_vector_type(8))) short bf16x8;
typedef __attribute__((ext_vector_type(4))) float f32x4;

struct alignas(8) US4 { unsigned short x, y, z, w; };

// round-to-nearest bf16 split: v = hi + lo + O(2^-17 v)
__device__ inline void bsplit(float v, unsigned short& hi, unsigned short& lo) {
    unsigned int u  = __builtin_bit_cast(unsigned int, v);
    unsigned int hb = (u + 0x7fffu + ((u >> 16) & 1u)) >> 16;
    hi = (unsigned short)hb;
    float fh = __builtin_bit_cast(float, hb << 16);
    float r  = v - fh;                      // exact (Sterbenz)
    unsigned int u2 = __builtin_bit_cast(unsigned int, r);
    lo = (unsigned short)((u2 + 0x7fffu + ((u2 >> 16) & 1u)) >> 16);
}

// pre-pass: W1[:, :, :128] fp32 -> bf16 hi/lo, layout [l*64+h][128]
__global__ __launch_bounds__(256)
void conv_w1(const float* __restrict__ W1g, unsigned short* __restrict__ W1h,
             unsigned short* __restrict__ W1l) {
    const int i   = blockIdx.x * 256 + threadIdx.x;   // 0..131071
    const int row = i >> 5;                           // 0..4095
    const int q   = (i & 31) << 2;                    // 0..124
    const float* src = W1g + (size_t)row * IN_DIM + q;
    unsigned short h[4], l[4];
    #pragma unroll
    for (int e = 0; e < 4; ++e) bsplit(src[e], h[e], l[e]);
    const size_t dst = (size_t)row * 128 + q;
    *reinterpret_cast<US4*>(W1h + dst) = US4{h[0], h[1], h[2], h[3]};
    *reinterpret_cast<US4*>(W1l + dst) = US4{l[0], l[1], l[2], l[3]};
}

__global__ __launch_bounds__(256, 2)
void fused_mfma(const float* __restrict__ xg, const float* __restrict__ W1g,
                const float* __restrict__ b1g, const float* __restrict__ W2g,
                const float* __restrict__ b2g,
                const unsigned short* __restrict__ W1h,
                const unsigned short* __restrict__ W1l,
                float* __restrict__ out_res, float* __restrict__ out_lad)
{
    __shared__ unsigned short sXh[XROWS][XSTR];
    __shared__ unsigned short sXl[XROWS][XSTR];
    __shared__ float sXt[XROWS][2];

    const int tid = threadIdx.x;
    const int bx  = blockIdx.x;           // 0..127 : 128-row M tile
    const int by  = blockIdx.y;           // 0..31  : pair of l
    const int bb  = bx >> 2;
    const int t0  = (bx & 3) * 128;
    const float* xbase = xg + ((size_t)bb * TROWS + t0) * LATENT;

    // ---- stage x tile: 130 rows x 64, bf16 hi/lo + fp32 xt columns ----
    for (int i = tid; i < XROWS * 16; i += 256) {
        const int row = i >> 4, c4 = (i & 15) << 2;
        const float4 v = *reinterpret_cast<const float4*>(xbase + row * LATENT + c4);
        unsigned short h0,h1,h2,h3, l0,l1,l2,l3;
        bsplit(v.x, h0, l0); bsplit(v.y, h1, l1);
        bsplit(v.z, h2, l2); bsplit(v.w, h3, l3);
        *reinterpret_cast<US4*>(&sXh[row][c4]) = US4{h0, h1, h2, h3};
        *reinterpret_cast<US4*>(&sXl[row][c4]) = US4{l0, l1, l2, l3};
    }
    for (int i = tid; i < XROWS * 2; i += 256) {
        const int row = i >> 1, w = i & 1;
        sXt[row][w] = xbase[row * LATENT + blockIdx.y * 2 + w];
    }
    __syncthreads();

    const int wave = tid >> 6;
    const int wm   = wave >> 1;           // 0..1 : 64-row half
    const int wn   = wave & 1;            // 0..1 : which l
    const int lane = tid & 63;
    const int r16  = lane & 15;
    const int kg   = lane >> 4;           // 0..3
    const int l    = blockIdx.y * 2 + wn;

    f32x4 acc[4][4];
    #pragma unroll
    for (int i = 0; i < 4; ++i)
        #pragma unroll
        for (int j = 0; j < 4; ++j) acc[i][j] = f32x4{0.f, 0.f, 0.f, 0.f};

    const unsigned short* Bh = W1h + (size_t)(l * HID + r16) * 128;
    const unsigned short* Bl = W1l + (size_t)(l * HID + r16) * 128;

    #pragma unroll
    for (int ks = 0; ks < 4; ++ks) {
        const int k0  = ks * 32 + kg * 8;
        const int lag = k0 >> 6;
        const int cc  = k0 & 63;
        bf16x8 ah[4], al[4];
        #pragma unroll
        for (int i = 0; i < 4; ++i) {
            const int rr = wm * 64 + i * 16 + r16 + lag;
            ah[i] = *reinterpret_cast<const bf16x8*>(&sXh[rr][cc]);
            al[i] = *reinterpret_cast<const bf16x8*>(&sXl[rr][cc]);
        }
        bf16x8 bh[4], bl[4];
        #pragma unroll
        for (int j = 0; j < 4; ++j) {
            bh[j] = *reinterpret_cast<const bf16x8*>(Bh + j * 16 * 128 + k0);
            bl[j] = *reinterpret_cast<const bf16x8*>(Bl + j * 16 * 128 + k0);
        }
        #pragma unroll
        for (int i = 0; i < 4; ++i)
            #pragma unroll
            for (int j = 0; j < 4; ++j) {
                acc[i][j] = __builtin_amdgcn_mfma_f32_16x16x32_bf16(ah[i], bh[j], acc[i][j], 0, 0, 0);
                acc[i][j] = __builtin_amdgcn_mfma_f32_16x16x32_bf16(ah[i], bl[j], acc[i][j], 0, 0, 0);
                acc[i][j] = __builtin_amdgcn_mfma_f32_16x16x32_bf16(al[i], bh[j], acc[i][j], 0, 0, 0);
            }
    }

    // ---- fused epilogue ----
    float w1t[4], w2v[4], b1v[4];
    #pragma unroll
    for (int j = 0; j < 4; ++j) {
        const int h = j * 16 + r16;
        const size_t base = (size_t)l * HID + h;
        w1t[j] = W1g[base * IN_DIM + 128];
        b1v[j] = b1g[base];
        w2v[j] = W2g[base];
    }
    const float b2v = b2g[l];

    #pragma unroll
    for (int i = 0; i < 4; ++i) {
        #pragma unroll
        for (int reg = 0; reg < 4; ++reg) {
            const int n_loc = wm * 64 + i * 16 + kg * 4 + reg;
            const float xt = sXt[n_loc + 2][wn];
            float res = 0.f, jv = 0.f;
            #pragma unroll
            for (int j = 0; j < 4; ++j) {
                const float pre = acc[i][j][reg] + xt * w1t[j] + b1v[j];
                const bool  p   = pre >= 0.f;
                const float act = p ? pre : SLOPE * pre;
                const float da  = p ? 1.f : SLOPE;
                res += act * w2v[j];
                jv  += w2v[j] * da * w1t[j];
            }
            #pragma unroll
            for (int m = 1; m <= 8; m <<= 1) {
                res += __shfl_xor(res, m);
                jv  += __shfl_xor(jv, m);
            }
            if (r16 == 0) {
                const int ng = bx * 128 + n_loc;
                out_res[(size_t)ng * LATENT + l] = res + b2v;
                atomicAdd(&out_lad[ng], logf(fabsf(jv)));
            }
        }
    }
}

extern "C" void kernel_launch(void* const* d_in, const int* in_sizes, int n_in,
                              void* d_out, int out_size, void* d_ws, size_t ws_size,
                              hipStream_t stream) {
    const float* xg  = (const float*)d_in[0];
    const float* W1g = (const float*)d_in[1];
    const float* b1g = (const float*)d_in[2];
    const float* W2g = (const float*)d_in[3];
    const float* b2g = (const float*)d_in[4];

    float* out_res = (float*)d_out;
    float* out_lad = out_res + (size_t)NTOT * LATENT;

    unsigned short* W1h = (unsigned short*)d_ws;        // 4096*128 ushort = 1 MB
    unsigned short* W1l = W1h + 4096 * 128;             // 1 MB

    hipMemsetAsync(out_lad, 0, (size_t)NTOT * sizeof(float), stream);
    conv_w1<<<512, 256, 0, stream>>>(W1g, W1h, W1l);

    dim3 grid(128, 32);
    fused_mfma<<<grid, 256, 0, stream>>>(xg, W1g, b1g, W2g, b2g, W1h, W1l,
                                         out_res, out_lad);
}

// Round 4
// 153.249 us; speedup vs baseline: 2.1177x; 1.1771x over previous
//
#include <hip/hip_runtime.h>
#include <math.h>

#define SLOPE  0.2f
#define NB     32
#define LEN    512
#define LATENT 64
#define HID    64
#define IN_DIM 129
#define TROWS  514
#define NTOT   (NB * LEN)      // 16384

typedef __attribute__((ext_vector_type(8)))  short bf16x8;
typedef __attribute__((ext_vector_type(16))) float f32x16;
typedef __attribute__((ext_vector_type(4)))  float f32x4;

struct alignas(8) US4 { unsigned short x, y, z, w; };

// round-to-nearest bf16 split: v = hi + lo + O(2^-18 v)
__device__ inline void bsplit(float v, unsigned short& hi, unsigned short& lo) {
    unsigned int u  = __builtin_bit_cast(unsigned int, v);
    unsigned int hb = (u + 0x7fffu + ((u >> 16) & 1u)) >> 16;
    hi = (unsigned short)hb;
    float fh = __builtin_bit_cast(float, hb << 16);
    float r  = v - fh;                      // exact (Sterbenz)
    unsigned int u2 = __builtin_bit_cast(unsigned int, r);
    lo = (unsigned short)((u2 + 0x7fffu + ((u2 >> 16) & 1u)) >> 16);
}

// pre-pass: W1[:, :, :128] fp32 -> bf16 hi/lo [4096][128]; W1[:, :, 128] -> W1t fp32
__global__ __launch_bounds__(256)
void conv_w1(const float* __restrict__ W1g, unsigned short* __restrict__ W1h,
             unsigned short* __restrict__ W1l, float* __restrict__ W1t) {
    const int i   = blockIdx.x * 256 + threadIdx.x;   // 0..131071
    const int row = i >> 5;                           // 0..4095
    const int q   = (i & 31) << 2;                    // 0..124
    const float* src = W1g + (size_t)row * IN_DIM + q;
    unsigned short h[4], lo[4];
    #pragma unroll
    for (int e = 0; e < 4; ++e) bsplit(src[e], h[e], lo[e]);
    const size_t dst = (size_t)row * 128 + q;
    *reinterpret_cast<US4*>(W1h + dst) = US4{h[0], h[1], h[2], h[3]};
    *reinterpret_cast<US4*>(W1l + dst) = US4{lo[0], lo[1], lo[2], lo[3]};
    if (q == 124) W1t[row] = src[4];                  // element 128
}

// block: 64 n-rows x 4 latents (1 wave per latent). wave tile: 64h x 64n.
__global__ __launch_bounds__(256, 3)
void fused_mfma(const float* __restrict__ xg,
                const float* __restrict__ b1g, const float* __restrict__ W2g,
                const float* __restrict__ b2g,
                const unsigned short* __restrict__ W1h,
                const unsigned short* __restrict__ W1l,
                const float* __restrict__ W1t,
                float* __restrict__ out_res, float* __restrict__ out_lad)
{
    __shared__ unsigned short sXh[66][72];   // x hi, stride 144B (16B-aligned)
    __shared__ unsigned short sXl[66][72];   // x lo
    __shared__ float sXt[66][4];             // fp32 xt columns (4 l's)
    __shared__ float sJ[64][4];              // per-l jacobians

    const int tid = threadIdx.x;
    const int bx  = blockIdx.x;              // 0..255 : 64-row M tile
    const int by  = blockIdx.y;              // 0..15  : 4 latents
    const int bb  = bx >> 3;
    const int t0  = (bx & 7) * 64;
    const float* xbase = xg + ((size_t)bb * TROWS + t0) * LATENT;

    // ---- stage x tile: 66 rows x 64, bf16 hi/lo + fp32 xt columns ----
    for (int i = tid; i < 66 * 16; i += 256) {
        const int row = i >> 4, c4 = (i & 15) << 2;
        const float4 v = *reinterpret_cast<const float4*>(xbase + row * LATENT + c4);
        unsigned short h0,h1,h2,h3, l0,l1,l2,l3;
        bsplit(v.x, h0, l0); bsplit(v.y, h1, l1);
        bsplit(v.z, h2, l2); bsplit(v.w, h3, l3);
        *reinterpret_cast<US4*>(&sXh[row][c4]) = US4{h0, h1, h2, h3};
        *reinterpret_cast<US4*>(&sXl[row][c4]) = US4{l0, l1, l2, l3};
    }
    for (int i = tid; i < 66 * 4; i += 256) {
        const int row = i >> 2, w = i & 3;
        sXt[row][w] = xbase[row * LATENT + by * 4 + w];
    }
    __syncthreads();

    const int wn   = tid >> 6;               // 0..3 : which latent
    const int lane = tid & 63;
    const int r32  = lane & 31;
    const int hi32 = lane >> 5;
    const int l    = by * 4 + wn;

    // ---- acc init = b1 (C/D row h = i*32 + 4*hi32 + 8*g + m) ----
    f32x16 acc[2][2];
    #pragma unroll
    for (int i = 0; i < 2; ++i)
        #pragma unroll
        for (int g = 0; g < 4; ++g) {
            const f32x4 b14 = *reinterpret_cast<const f32x4*>(
                b1g + l * HID + i * 32 + hi32 * 4 + g * 8);
            #pragma unroll
            for (int m = 0; m < 4; ++m) {
                acc[i][0][g * 4 + m] = b14[m];
                acc[i][1][g * 4 + m] = b14[m];
            }
        }

    // ---- K loop: A = W1 rows (global/L2), B = x rows (LDS), bf16x3 ----
    const unsigned short* Ah = W1h + ((size_t)l * HID + r32) * 128;
    const unsigned short* Al = W1l + ((size_t)l * HID + r32) * 128;

    #pragma unroll
    for (int ks = 0; ks < 8; ++ks) {
        const int koff = ks * 16 + hi32 * 8;         // k position 0..120
        const int lag  = ks >> 2;                    // which lag block of x
        const int cc   = (ks & 3) * 16 + hi32 * 8;   // column within lag block
        bf16x8 awh[2], awl[2], bxh[2], bxl[2];
        #pragma unroll
        for (int i = 0; i < 2; ++i) {
            awh[i] = *reinterpret_cast<const bf16x8*>(Ah + i * 32 * 128 + koff);
            awl[i] = *reinterpret_cast<const bf16x8*>(Al + i * 32 * 128 + koff);
        }
        #pragma unroll
        for (int j = 0; j < 2; ++j) {
            const int rr = j * 32 + r32 + lag;
            bxh[j] = *reinterpret_cast<const bf16x8*>(&sXh[rr][cc]);
            bxl[j] = *reinterpret_cast<const bf16x8*>(&sXl[rr][cc]);
        }
        #pragma unroll
        for (int i = 0; i < 2; ++i)
            #pragma unroll
            for (int j = 0; j < 2; ++j) {
                acc[i][j] = __builtin_amdgcn_mfma_f32_32x32x16_bf16(awh[i], bxh[j], acc[i][j], 0, 0, 0);
                acc[i][j] = __builtin_amdgcn_mfma_f32_32x32x16_bf16(awh[i], bxl[j], acc[i][j], 0, 0, 0);
                acc[i][j] = __builtin_amdgcn_mfma_f32_32x32x16_bf16(awl[i], bxh[j], acc[i][j], 0, 0, 0);
            }
    }

    // ---- fused epilogue: h lives in (i, reg, hi32); n = j*32 + r32 ----
    const float xt0 = sXt[r32 + 2][wn];
    const float xt1 = sXt[32 + r32 + 2][wn];
    float res0 = 0.f, res1 = 0.f, jp0 = 0.f, jp1 = 0.f, jc = 0.f;

    #pragma unroll
    for (int i = 0; i < 2; ++i)
        #pragma unroll
        for (int g = 0; g < 4; ++g) {
            const int h0 = l * HID + i * 32 + hi32 * 4 + g * 8;
            const f32x4 wt = *reinterpret_cast<const f32x4*>(W1t + h0);
            const f32x4 w2 = *reinterpret_cast<const f32x4*>(W2g + h0);
            #pragma unroll
            for (int m = 0; m < 4; ++m) {
                const float c0 = w2[m] * wt[m];
                jc += c0;
                const int r = g * 4 + m;
                const float pre0 = fmaf(xt0, wt[m], acc[i][0][r]);
                const float pre1 = fmaf(xt1, wt[m], acc[i][1][r]);
                res0 += w2[m] * fmaxf(pre0, SLOPE * pre0);
                res1 += w2[m] * fmaxf(pre1, SLOPE * pre1);
                jp0 += (pre0 >= 0.f) ? c0 : 0.f;
                jp1 += (pre1 >= 0.f) ? c0 : 0.f;
            }
        }

    res0 += __shfl_xor(res0, 32);
    res1 += __shfl_xor(res1, 32);
    jp0  += __shfl_xor(jp0, 32);
    jp1  += __shfl_xor(jp1, 32);
    jc   += __shfl_xor(jc, 32);
    const float jac0 = SLOPE * jc + (1.f - SLOPE) * jp0;
    const float jac1 = SLOPE * jc + (1.f - SLOPE) * jp1;

    if (hi32 == 0) {
        const float b2v = b2g[l];
        const size_t n0 = (size_t)bx * 64 + r32;
        out_res[n0 * LATENT + l]        = res0 + b2v;
        out_res[(n0 + 32) * LATENT + l] = res1 + b2v;
        sJ[r32][wn]      = jac0;
        sJ[r32 + 32][wn] = jac1;
    }
    __syncthreads();
    if (tid < 64) {
        const float p = sJ[tid][0] * sJ[tid][1] * sJ[tid][2] * sJ[tid][3];
        atomicAdd(&out_lad[bx * 64 + tid], logf(fabsf(p)));
    }
}

extern "C" void kernel_launch(void* const* d_in, const int* in_sizes, int n_in,
                              void* d_out, int out_size, void* d_ws, size_t ws_size,
                              hipStream_t stream) {
    const float* xg  = (const float*)d_in[0];
    const float* W1g = (const float*)d_in[1];
    const float* b1g = (const float*)d_in[2];
    const float* W2g = (const float*)d_in[3];
    const float* b2g = (const float*)d_in[4];

    float* out_res = (float*)d_out;
    float* out_lad = out_res + (size_t)NTOT * LATENT;

    float*          W1t = (float*)d_ws;                   // 16 KB
    unsigned short* W1h = (unsigned short*)(W1t + 4096);  // 1 MB
    unsigned short* W1l = W1h + 4096 * 128;               // 1 MB

    hipMemsetAsync(out_lad, 0, (size_t)NTOT * sizeof(float), stream);
    conv_w1<<<512, 256, 0, stream>>>(W1g, W1h, W1l, W1t);

    dim3 grid(256, 16);  // (64-row n-tiles, latent quads)
    fused_mfma<<<grid, 256, 0, stream>>>(xg, b1g, W2g, b2g, W1h, W1l, W1t,
                                         out_res, out_lad);
}